// Round 7
// baseline (96.853 us; speedup 1.0000x reference)
//
#include <hip/hip_runtime.h>

#define MARGIN 0.3f

typedef __attribute__((ext_vector_type(8))) short short8;
typedef __attribute__((ext_vector_type(16))) float floatx16;

// ---- helpers ----------------------------------------------------------------

// order-preserving float->uint encoding so unsigned atomicMin == float min
__device__ __forceinline__ unsigned enc_f32(float f) {
    unsigned u = __float_as_uint(f);
    return (u & 0x80000000u) ? ~u : (u | 0x80000000u);
}
__device__ __forceinline__ float dec_f32(unsigned u) {
    return (u & 0x80000000u) ? __uint_as_float(u & 0x7fffffffu)
                             : __uint_as_float(~u);
}
// fp32 -> bf16 bits, round-to-nearest-even
__device__ __forceinline__ short f2bf(float f) {
    unsigned u = __float_as_uint(f);
    u = u + 0x7fffu + ((u >> 16) & 1u);
    return (short)(u >> 16);
}

// direct global->LDS DMA (no VGPR round-trip). LDS dest is wave-uniform
// base + lane*size — all call sites below respect that.
__device__ __forceinline__ void gload_lds16(const void* g, void* l) {
    __builtin_amdgcn_global_load_lds(
        (const __attribute__((address_space(1))) void*)g,
        (__attribute__((address_space(3))) void*)l, 16, 0, 0);
}
__device__ __forceinline__ void gload_lds4(const void* g, void* l) {
    __builtin_amdgcn_global_load_lds(
        (const __attribute__((address_space(1))) void*)g,
        (__attribute__((address_space(3))) void*)l, 4, 0, 0);
}

// Fragment-native global layout: element (row, k) with g16=row/16, r=row%16,
// kk=k/32, q=(k%32)/8, e=k%8 lives at  g16*2048 + kk*512 + q*128 + r*8 + e.
// For the 32x32x16 MFMA, lane l needs (row = base+ (l&31), k = kk16*16 +
// (l>>5)*8 + 0..7): that is g16 = base/16 + ((l>>4)&1), kk = kk16>>1,
// q = (kk16&1)*2 + (l>>5), r = l&15  ->  STILL a contiguous 16 B read per
// lane, at base_l + compile-time immediate offsets. Same layout serves both
// MFMA shapes; the global->LDS stage stays a linear memcpy.

// ---- kernel 1: prepass (identical to R4) ------------------------------------
__global__ void prep_kernel(const float* __restrict__ z1, const float* __restrict__ z2,
                            short* __restrict__ z1b, short* __restrict__ z2b,
                            float* __restrict__ sq1, float* __restrict__ sq2,
                            float* __restrict__ posd, unsigned* __restrict__ rowmin,
                            unsigned* __restrict__ cnt, float* __restrict__ out) {
    int h = blockIdx.x * 256 + threadIdx.x;     // 0 .. n*16-1
    int row = h >> 4, p = h & 15;
    int kk = p >> 2, q = p & 3;
    int f0 = row * 32 + kk * 8 + q * 2;         // first float4 index
    float4 fa0 = ((const float4*)z1)[f0], fa1 = ((const float4*)z1)[f0 + 1];
    float4 fb0 = ((const float4*)z2)[f0], fb1 = ((const float4*)z2)[f0 + 1];
    short8 sa = { f2bf(fa0.x), f2bf(fa0.y), f2bf(fa0.z), f2bf(fa0.w),
                  f2bf(fa1.x), f2bf(fa1.y), f2bf(fa1.z), f2bf(fa1.w) };
    // B pre-scaled by -2 (exact): GEMM accumulates a * (-2b)
    short8 sb = { f2bf(-2.f*fb0.x), f2bf(-2.f*fb0.y), f2bf(-2.f*fb0.z), f2bf(-2.f*fb0.w),
                  f2bf(-2.f*fb1.x), f2bf(-2.f*fb1.y), f2bf(-2.f*fb1.z), f2bf(-2.f*fb1.w) };
    size_t off = (size_t)(row >> 4) * 2048 + kk * 512 + q * 128 + (row & 15) * 8;
    __builtin_nontemporal_store(sa, (short8*)&z1b[off]);
    __builtin_nontemporal_store(sb, (short8*)&z2b[off]);

    float s1 = fa0.x*fa0.x + fa0.y*fa0.y + fa0.z*fa0.z + fa0.w*fa0.w
             + fa1.x*fa1.x + fa1.y*fa1.y + fa1.z*fa1.z + fa1.w*fa1.w;
    float s2 = fb0.x*fb0.x + fb0.y*fb0.y + fb0.z*fb0.z + fb0.w*fb0.w
             + fb1.x*fb1.x + fb1.y*fb1.y + fb1.z*fb1.z + fb1.w*fb1.w;
    float dx0 = fa0.x-fb0.x, dy0 = fa0.y-fb0.y, dz0 = fa0.z-fb0.z, dw0 = fa0.w-fb0.w;
    float dx1 = fa1.x-fb1.x, dy1 = fa1.y-fb1.y, dz1 = fa1.z-fb1.z, dw1 = fa1.w-fb1.w;
    float p2 = dx0*dx0 + dy0*dy0 + dz0*dz0 + dw0*dw0
             + dx1*dx1 + dy1*dy1 + dz1*dz1 + dw1*dw1;
    #pragma unroll
    for (int m = 8; m >= 1; m >>= 1) {          // 16 threads per row
        s1 += __shfl_xor(s1, m);
        s2 += __shfl_xor(s2, m);
        p2 += __shfl_xor(p2, m);
    }
    if (p == 0) {
        __builtin_nontemporal_store(s1, &sq1[row]);
        __builtin_nontemporal_store(s2, &sq2[row]);
        __builtin_nontemporal_store(sqrtf(p2), &posd[row]);
    }

    if (threadIdx.x < 16)
        __builtin_nontemporal_store(0xFFFFFFFFu, &rowmin[blockIdx.x * 16 + threadIdx.x]);
    if (blockIdx.x == 0) {
        if (threadIdx.x < 32) cnt[threadIdx.x] = 0u;
        if (threadIdx.x == 0) out[0] = 0.0f;
    }
}

// ---- kernel 2: 512x512 tile, 32x32x16-MFMA core (instruction-thinned) -------
// R7: identical structure to R4 (grid 256 = 1 block/CU, 8 waves, full-panel
// prologue DMA, counted vmcnt, XCD-bijective swizzle) — only the compute core
// changes: 32 x mfma_f32_32x32x16_bf16 per superphase instead of 64 x
// 16x16x32 (same FLOPs, half the MFMA issue slots), with ds_read_b128 B-frag
// reads at compile-time immediate offsets off one base (address VALU ~gone).
// Rationale: counters imply the kernel runs at idle DVFS clocks (~420 MHz;
// R5's MfmaUtil=14.4% matches 256 MFMA/wave at 420 MHz exactly), so dur is
// issue-throughput-bound -> cut issued instructions, not latency.
// C/D layout (verified m74/m101): col = lane&31, row = (reg&3)+8*(reg>>2)+
// 4*(lane>>5). A/B operand: lane l holds 8 consecutive k at row/col = l&31,
// k = kk16*16 + (l>>5)*8.
__global__ __launch_bounds__(512, 2)
void gemm_min_kernel(const short* __restrict__ z1b, const short* __restrict__ z2b,
                     const float* __restrict__ sq1, const float* __restrict__ sq2,
                     const float* __restrict__ posd,
                     unsigned* __restrict__ rowmin, unsigned* __restrict__ cnt,
                     float* __restrict__ out, int n)
{
    __shared__ __align__(16) short sb[8][8192];   // 8 x (64 cols x 128 k) bf16
    __shared__ __align__(16) float s2l[512];      // sq2 slice for block's cols
    __shared__ float lsum[8];
    __shared__ int   fin_s;

    // bijective XCD swizzle (256 blocks = 8 xcd x 32, exact)
    const int bid = blockIdx.x;
    const int xcd = bid & 7, idx = bid >> 3;      // idx 0..31
    const int rg  = (xcd << 1) | (idx >> 4);      // row-group 0..15
    const int cgi = idx & 15;                     // col-group 0..15

    const int tid = threadIdx.x, w = tid >> 6, lane = tid & 63;
    const int l31 = lane & 31, hi = lane >> 5;    // 32x32 operand coords
    const int rowbase = rg * 512 + w * 64;        // this wave's 64 rows
    const int colorig = cgi * 512;

    const short* gb = z2b + (size_t)(cgi * 32) * 2048;   // block's B panel

    // per-lane byte offset inside a fragment-native 64-row/col group:
    // ((lane>>4)&1)*2048 + (lane>>5)*128 + (lane&15)*8   [shorts]
    const int lofs = ((lane >> 4) & 1) * 2048 + hi * 128 + (lane & 15) * 8;

    // ---- prologue: issue EVERYTHING. per-wave vmem issue order (uniform):
    //   buf0 (2) | s2l (1) | af (16) | buf1..7 (2 each) = 33 outstanding.
    // sched_barrier(0) pins group order so counted vmcnt stays sound.
    #pragma unroll
    for (int o = 0; o < 2; ++o)
        gload_lds16(gb + (tid + o * 512) * 8, &sb[0][(tid + o * 512) * 8]);
    __builtin_amdgcn_sched_barrier(0);
    gload_lds4(sq2 + colorig + tid, &s2l[tid]);
    __builtin_amdgcn_sched_barrier(0);

    // persistent A fragments for 32x32x16: af[rb][kk16] =
    // A[rowbase + rb*32 + l31][kk16*16 + hi*8 .. +7]   (16 x b128, coalesced)
    short8 af[2][8];
    {
        const short* pa = z1b + (size_t)(rg * 32 + w * 4) * 2048 + lofs;
        #pragma unroll
        for (int rb = 0; rb < 2; ++rb)
            #pragma unroll
            for (int kk16 = 0; kk16 < 8; ++kk16)
                af[rb][kk16] = *(const short8*)(pa + rb * 4096
                                + (kk16 >> 1) * 512 + (kk16 & 1) * 256);
    }
    __builtin_amdgcn_sched_barrier(0);
    #pragma unroll
    for (int s = 1; s < 8; ++s) {
        #pragma unroll
        for (int o = 0; o < 2; ++o)
            gload_lds16(gb + (size_t)s * 8192 + (tid + o * 512) * 8,
                        &sb[s][(tid + o * 512) * 8]);
        __builtin_amdgcn_sched_barrier(0);
    }

    float vmin[2][16];
    #pragma unroll
    for (int rb = 0; rb < 2; ++rb)
        #pragma unroll
        for (int r = 0; r < 16; ++r)
            vmin[rb][r] = 3.0e38f;

    // superphase S: wait own stage loads for buf S (counted — later bufs stay
    // in flight), barrier for cross-wave visibility, then pure LDS+MFMA+fmin.
#define SUPERPHASE(S, VMTXT)                                                   \
    do {                                                                       \
        asm volatile("s_waitcnt vmcnt(" VMTXT ")" ::: "memory");               \
        __builtin_amdgcn_sched_barrier(0);                                     \
        __builtin_amdgcn_s_barrier();                                          \
        __builtin_amdgcn_sched_barrier(0);                                     \
        const short* bs_ = &sb[S][0] + lofs;                                   \
        const float s2v0 = s2l[(S) * 64 + l31];                                \
        const float s2v1 = s2l[(S) * 64 + 32 + l31];                           \
        floatx16 acc[2][2];                                                    \
        _Pragma("unroll")                                                      \
        for (int rb = 0; rb < 2; ++rb)                                         \
            _Pragma("unroll")                                                  \
            for (int r = 0; r < 16; ++r) {                                     \
                acc[rb][0][r] = s2v0;                                          \
                acc[rb][1][r] = s2v1;                                          \
            }                                                                  \
        __builtin_amdgcn_s_setprio(1);                                         \
        _Pragma("unroll")                                                      \
        for (int kk16 = 0; kk16 < 8; ++kk16) {                                 \
            short8 b0 = *(const short8*)(bs_ + (kk16 >> 1) * 512               \
                                         + (kk16 & 1) * 256);                  \
            short8 b1 = *(const short8*)(bs_ + 4096 + (kk16 >> 1) * 512        \
                                         + (kk16 & 1) * 256);                  \
            acc[0][0] = __builtin_amdgcn_mfma_f32_32x32x16_bf16(               \
                af[0][kk16], b0, acc[0][0], 0, 0, 0);                          \
            acc[1][0] = __builtin_amdgcn_mfma_f32_32x32x16_bf16(               \
                af[1][kk16], b0, acc[1][0], 0, 0, 0);                          \
            acc[0][1] = __builtin_amdgcn_mfma_f32_32x32x16_bf16(               \
                af[0][kk16], b1, acc[0][1], 0, 0, 0);                          \
            acc[1][1] = __builtin_amdgcn_mfma_f32_32x32x16_bf16(               \
                af[1][kk16], b1, acc[1][1], 0, 0, 0);                          \
        }                                                                      \
        __builtin_amdgcn_s_setprio(0);                                         \
        _Pragma("unroll")                                                      \
        for (int cb = 0; cb < 2; ++cb) {                                       \
            const int cbcol = colorig + (S) * 64 + cb * 32;                    \
            if (cbcol < rowbase + 64 && rowbase < cbcol + 32) {                \
                _Pragma("unroll")                                              \
                for (int rb = 0; rb < 2; ++rb)                                 \
                    _Pragma("unroll")                                          \
                    for (int r = 0; r < 16; ++r) {                             \
                        int gi = rowbase + rb * 32 + (r & 3) + 8 * (r >> 2)    \
                                 + 4 * hi;                                     \
                        float v = acc[rb][cb][r];                              \
                        v = (gi == cbcol + l31) ? 3.0e38f : v;                 \
                        vmin[rb][r] = fminf(vmin[rb][r], v);                   \
                    }                                                          \
            } else {                                                           \
                _Pragma("unroll")                                              \
                for (int rb = 0; rb < 2; ++rb)                                 \
                    _Pragma("unroll")                                          \
                    for (int r = 0; r < 16; ++r)                               \
                        vmin[rb][r] = fminf(vmin[rb][r], acc[rb][cb][r]);      \
            }                                                                  \
        }                                                                      \
    } while (0)

    SUPERPHASE(0, "14");
    SUPERPHASE(1, "12");
    SUPERPHASE(2, "10");
    SUPERPHASE(3, "8");
    SUPERPHASE(4, "6");
    SUPERPHASE(5, "4");
    SUPERPHASE(6, "2");
    SUPERPHASE(7, "0");
#undef SUPERPHASE

    // min across the 32 lanes holding each row's cols, one atomicMin per row.
    // Row of (rb, r, hi-half): rowbase + rb*32 + (r&3) + 8*(r>>2) + 4*hi;
    // its 32 cols live in lanes {hi*32 + 0..31}: reduce within each half.
    #pragma unroll
    for (int rb = 0; rb < 2; ++rb)
        #pragma unroll
        for (int r = 0; r < 16; ++r) {
            float vm = vmin[rb][r];
            #pragma unroll
            for (int m = 16; m >= 1; m >>= 1)
                vm = fminf(vm, __shfl_xor(vm, m));
            if (l31 == 0)
                atomicMin(&rowmin[rowbase + rb * 32 + (r & 3) + 8 * (r >> 2) + 4 * hi],
                          enc_f32(vm));
        }

    __syncthreads();
    if (tid == 0) {
        __threadfence();    // release: this block's mins visible before bump
        fin_s = (atomicAdd(&cnt[rg], 1u) == 15u);   // 16 col-blocks per rg
    }
    __syncthreads();
    if (!fin_s) return;
    __threadfence();        // acquire: see all 16 blocks' mins

    // fused loss for rows [rg*512, rg*512+512): thread = one row
    {
        int i = rg * 512 + tid;
        unsigned rm = atomicMin(&rowmin[i], 0xFFFFFFFFu);   // coherent forced read
        float hard = sqrtf(fmaxf(sq1[i] + dec_f32(rm), 0.0f));
        float l = fmaxf(posd[i] - hard + MARGIN, 0.0f);
        #pragma unroll
        for (int m = 32; m >= 1; m >>= 1) l += __shfl_xor(l, m);
        if (lane == 0) lsum[w] = l;
    }
    __syncthreads();
    if (tid == 0) {
        float t = 0.f;
        #pragma unroll
        for (int i = 0; i < 8; ++i) t += lsum[i];
        atomicAdd(out, t / (float)n);
    }
}

// ---- launch -----------------------------------------------------------------
extern "C" void kernel_launch(void* const* d_in, const int* in_sizes, int n_in,
                              void* d_out, int out_size, void* d_ws, size_t ws_size,
                              hipStream_t stream) {
    const float* z1 = (const float*)d_in[0];
    const float* z2 = (const float*)d_in[1];
    const int n = in_sizes[0] / 128;            // 8192

    char* ws = (char*)d_ws;
    short*    z1b    = (short*)ws;                                     // 2 MB
    short*    z2b    = (short*)(ws + (size_t)n * 128 * 2);             // 2 MB
    float*    sq1    = (float*)(ws + (size_t)n * 128 * 4);             // 32 KB
    float*    sq2    = (float*)(ws + (size_t)n * 128 * 4 + n * 4);     // 32 KB
    float*    posd   = (float*)(ws + (size_t)n * 128 * 4 + n * 8);     // 32 KB
    unsigned* rowmin = (unsigned*)(ws + (size_t)n * 128 * 4 + n * 12); // 32 KB
    unsigned* cnt    = (unsigned*)(ws + (size_t)n * 128 * 4 + n * 16); // 128 B
    float*    out    = (float*)d_out;

    prep_kernel<<<n / 16, 256, 0, stream>>>(z1, z2, z1b, z2b, sq1, sq2, posd,
                                            rowmin, cnt, out);
    gemm_min_kernel<<<(n / 512) * (n / 512), 512, 0, stream>>>(
        z1b, z2b, sq1, sq2, posd, rowmin, cnt, out, n);
}